// Round 1
// baseline (712.651 us; speedup 1.0000x reference)
//
#include <hip/hip_runtime.h>

#define M_TOTAL 12544
#define IN_D 768
#define OUT_D 768
#define NUM_F 8
#define KTOT (IN_D * (NUM_F + 1))   // 6912
#define BM 128
#define BN 128
#define BK 32
#define NT (KTOT / BK)              // 216

typedef __attribute__((ext_vector_type(8))) short short8;
typedef __attribute__((ext_vector_type(4))) float f32x4;

__device__ __forceinline__ unsigned short f2bf(float f) {
  unsigned u = __float_as_uint(f);
  u += 0x7fff + ((u >> 16) & 1);   // RNE
  return (unsigned short)(u >> 16);
}

__global__ __launch_bounds__(256, 2) void skan_kernel(
    const float* __restrict__ x, const float* __restrict__ bw,
    const float* __restrict__ grid, const float* __restrict__ ssp,
    const float* __restrict__ coef, const float* __restrict__ cw,
    const float* __restrict__ cb, float* __restrict__ out)
{
  // fragment-major LDS: granule index = kb*128 + row ; each granule = 8 bf16 (16B)
  __shared__ short8 Asm[2][512];
  __shared__ short8 Bsm[2][512];
  __shared__ float bias_sm[BN];

  const int tid = threadIdx.x;
  const int bid = blockIdx.x;
  const int tn = bid % (OUT_D / BN);
  const int tm = bid / (OUT_D / BN);
  const int m0 = tm * BM, n0 = tn * BN;

  const int lane = tid & 63, wid = tid >> 6;
  const int wm = wid >> 1, wn = wid & 1;       // 2x2 wave grid, 64x64 per wave
  const int lrow = lane & 15, lkb = lane >> 4;

  // bias[o] = scale_sp[o] * sum_f conv_b[f][o]
  if (tid < BN) {
    int o = n0 + tid;
    float s = 0.f;
    #pragma unroll
    for (int f = 0; f < NUM_F; ++f) s += cb[f * OUT_D + o];
    bias_sm[tid] = s * ssp[o];
  }

  // staging map: thread -> (row rA in tile, 16-col half hA); produces granules
  // (hA*2, rA) and (hA*2+1, rA) for both A and B tiles.
  const int rA = tid >> 1;
  const int hA = tid & 1;
  const float* xrow = x + (size_t)(m0 + rA) * IN_D + hA * 16;
  const int oB = n0 + rA;
  const float sspB = ssp[oB];
  const int g0 = hA * 2 * 128 + rA;   // first granule index
  const int g1 = g0 + 128;            // second granule index

  f32x4 xa[4], wb[4];   // staged fp32 for next tile

  auto LD = [&](int p_, int i0_) {
    const f32x4* xp = (const f32x4*)(xrow + i0_);
    xa[0] = xp[0]; xa[1] = xp[1]; xa[2] = xp[2]; xa[3] = xp[3];
    const float* wbase = (p_ == 0)
        ? (bw + (size_t)oB * IN_D)
        : (cw + ((size_t)(p_ - 1) * OUT_D + oB) * IN_D);
    const f32x4* wp = (const f32x4*)(wbase + hA * 16 + i0_);
    wb[0] = wp[0]; wb[1] = wp[1]; wb[2] = wp[2]; wb[3] = wp[3];
  };

  auto STAGE = [&](int buf, int p_, int i0_) {
    float v[16];
    #pragma unroll
    for (int q = 0; q < 4; ++q)
      #pragma unroll
      for (int e = 0; e < 4; ++e) v[q * 4 + e] = xa[q][e];

    unsigned short abf[16];
    if (p_ == 0) {
      #pragma unroll
      for (int j = 0; j < 16; ++j) {
        float t = v[j];
        float den = 1.f + __expf(-t);
        abf[j] = f2bf(t * __builtin_amdgcn_rcpf(den));
      }
    } else {
      float g = grid[p_ - 1];
      const float* cp = coef + (size_t)(i0_ + hA * 16) * NUM_F + (p_ - 1);
      #pragma unroll
      for (int j = 0; j < 16; ++j)
        abf[j] = f2bf(__sinf(v[j] * g) * cp[j * NUM_F]);
    }
    short8 s0, s1;
    #pragma unroll
    for (int e = 0; e < 8; ++e) { s0[e] = (short)abf[e]; s1[e] = (short)abf[8 + e]; }
    Asm[buf][g0] = s0;
    Asm[buf][g1] = s1;

    const float fac = (p_ == 0) ? 1.f : sspB;
    unsigned short bbf[16];
    #pragma unroll
    for (int q = 0; q < 4; ++q)
      #pragma unroll
      for (int e = 0; e < 4; ++e) bbf[q * 4 + e] = f2bf(wb[q][e] * fac);
    short8 t0, t1;
    #pragma unroll
    for (int e = 0; e < 8; ++e) { t0[e] = (short)bbf[e]; t1[e] = (short)bbf[8 + e]; }
    Bsm[buf][g0] = t0;
    Bsm[buf][g1] = t1;
  };

  f32x4 acc[4][4];
  #pragma unroll
  for (int i = 0; i < 4; ++i)
    #pragma unroll
    for (int j = 0; j < 4; ++j)
      acc[i][j] = (f32x4){0.f, 0.f, 0.f, 0.f};

  int p = 0, i0 = 0;
  LD(0, 0);
  STAGE(0, 0, 0);
  __syncthreads();

  for (int t = 0; t < NT; ++t) {
    const int cur = t & 1;
    int p1 = p, i1 = i0 + BK;
    if (i1 == IN_D) { i1 = 0; p1 = p + 1; }
    if (t + 1 < NT) LD(p1, i1);

    short8 af[4], bfr[4];
    #pragma unroll
    for (int q = 0; q < 4; ++q) {
      af[q]  = Asm[cur][lkb * 128 + wm * 64 + q * 16 + lrow];
      bfr[q] = Bsm[cur][lkb * 128 + wn * 64 + q * 16 + lrow];
    }
    #pragma unroll
    for (int i = 0; i < 4; ++i)
      #pragma unroll
      for (int j = 0; j < 4; ++j)
        acc[i][j] = __builtin_amdgcn_mfma_f32_16x16x32_bf16(af[i], bfr[j], acc[i][j], 0, 0, 0);

    if (t + 1 < NT) STAGE(cur ^ 1, p1, i1);
    p = p1; i0 = i1;
    __syncthreads();
  }

  // epilogue: C/D layout col=lane&15, row=(lane>>4)*4+reg
  #pragma unroll
  for (int i = 0; i < 4; ++i) {
    int row = m0 + wm * 64 + i * 16 + lkb * 4;
    #pragma unroll
    for (int j = 0; j < 4; ++j) {
      int col = n0 + wn * 64 + j * 16 + lrow;
      float bia = bias_sm[wn * 64 + j * 16 + lrow];
      float* op = out + (size_t)row * OUT_D + col;
      op[0 * OUT_D] = acc[i][j][0] + bia;
      op[1 * OUT_D] = acc[i][j][1] + bia;
      op[2 * OUT_D] = acc[i][j][2] + bia;
      op[3 * OUT_D] = acc[i][j][3] + bia;
    }
  }
}

extern "C" void kernel_launch(void* const* d_in, const int* in_sizes, int n_in,
                              void* d_out, int out_size, void* d_ws, size_t ws_size,
                              hipStream_t stream) {
  (void)in_sizes; (void)n_in; (void)out_size; (void)d_ws; (void)ws_size;
  const float* x    = (const float*)d_in[0];
  const float* bw   = (const float*)d_in[1];
  const float* grid = (const float*)d_in[2];
  const float* ssp  = (const float*)d_in[3];
  const float* coef = (const float*)d_in[4];
  const float* cw   = (const float*)d_in[5];
  const float* cb   = (const float*)d_in[6];
  float* out = (float*)d_out;

  dim3 g((M_TOTAL / BM) * (OUT_D / BN));   // 98*6 = 588
  dim3 b(256);
  hipLaunchKernelGGL(skan_kernel, g, b, 0, stream, x, bw, grid, ssp, coef, cw, cb, out);
}

// Round 2
// 652.843 us; speedup vs baseline: 1.0916x; 1.0916x over previous
//
#include <hip/hip_runtime.h>

#define M_TOTAL 12544
#define IN_D 768
#define OUT_D 768
#define NUM_F 8
#define NP 9
#define KTOT (IN_D * NP)            // 6912

typedef __attribute__((ext_vector_type(8))) short short8;
typedef __attribute__((ext_vector_type(4))) float f32x4;

__device__ __forceinline__ unsigned short f2bf(float f) {
  unsigned u = __float_as_uint(f);
  u += 0x7fff + ((u >> 16) & 1);   // RNE
  return (unsigned short)(u >> 16);
}

// ---------------------------------------------------------------------------
// pack_a: A[m][p*768+i] = p==0 ? silu(x[m,i]) : sin(p*x[m,i])*coef[i,p-1]
// bf16, row-major [M][KTOT]. Each thread: 8 contiguous i, all 9 planes.
// ---------------------------------------------------------------------------
__global__ __launch_bounds__(256) void pack_a(
    const float* __restrict__ x, const float* __restrict__ grid,
    const float* __restrict__ coef, unsigned short* __restrict__ A)
{
  int gid = blockIdx.x * 256 + threadIdx.x;   // [0, 12544*96)
  int m = gid / 96, seg = gid % 96;
  const f32x4* xp = (const f32x4*)(x + (size_t)m * IN_D + seg * 8);
  f32x4 x0 = xp[0], x1 = xp[1];
  float xv[8] = {x0[0], x0[1], x0[2], x0[3], x1[0], x1[1], x1[2], x1[3]};
  float gv[8];
  #pragma unroll
  for (int p = 0; p < 8; ++p) gv[p] = grid[p];

  unsigned short res[NP][8];
  #pragma unroll
  for (int j = 0; j < 8; ++j) {
    float t = xv[j];
    res[0][j] = f2bf(t / (1.f + __expf(-t)));
  }
  #pragma unroll
  for (int j = 0; j < 8; ++j) {
    const f32x4* cp = (const f32x4*)(coef + (size_t)(seg * 8 + j) * NUM_F);
    f32x4 c0 = cp[0], c1 = cp[1];
    float cf[8] = {c0[0], c0[1], c0[2], c0[3], c1[0], c1[1], c1[2], c1[3]};
    #pragma unroll
    for (int p = 0; p < 8; ++p)
      res[p + 1][j] = f2bf(__sinf(xv[j] * gv[p]) * cf[p]);
  }
  unsigned short* dst = A + (size_t)m * KTOT + seg * 8;
  #pragma unroll
  for (int p = 0; p < NP; ++p) {
    short8 s;
    #pragma unroll
    for (int e = 0; e < 8; ++e) s[e] = (short)res[p][e];
    *(short8*)(dst + (size_t)p * IN_D) = s;
  }
}

// ---------------------------------------------------------------------------
// pack_b: Bt[o][p*768+i] = (p==0 ? bw[o][i] : cw[p-1][o][i]*ssp[o]) as bf16
// ---------------------------------------------------------------------------
__global__ __launch_bounds__(256) void pack_b(
    const float* __restrict__ bw, const float* __restrict__ ssp,
    const float* __restrict__ cw, unsigned short* __restrict__ B)
{
  int gid = blockIdx.x * 256 + threadIdx.x;   // [0, 768*9*96)
  int o = gid / (NP * 96);
  int rem = gid % (NP * 96);
  int p = rem / 96;
  int i0 = (rem % 96) * 8;
  const float* src = (p == 0) ? (bw + (size_t)o * IN_D + i0)
                              : (cw + ((size_t)(p - 1) * OUT_D + o) * IN_D + i0);
  float fac = (p == 0) ? 1.f : ssp[o];
  f32x4 v0 = ((const f32x4*)src)[0], v1 = ((const f32x4*)src)[1];
  short8 s;
  #pragma unroll
  for (int e = 0; e < 4; ++e) {
    s[e]     = (short)f2bf(v0[e] * fac);
    s[e + 4] = (short)f2bf(v1[e] * fac);
  }
  *(short8*)(B + (size_t)o * KTOT + p * IN_D + i0) = s;
}

// ---------------------------------------------------------------------------
// skan_gemm: out = A(bf16) @ Bt(bf16)^T + bias, m97 structure.
// 128x128 tile, BK=64, 4 waves (2x2, 64x64 each), dbuf LDS, global_load_lds.
// LDS layout: 16B granules, granule idx = kc*128 + row (kc-major: conflict-free)
// ---------------------------------------------------------------------------
#define BM 128
#define BN 128
#define BK 64
#define NT (KTOT / BK)              // 108
#define GRAN 1024                   // BM*BK/8 granules per tile

__global__ __launch_bounds__(256, 2) void skan_gemm(
    const unsigned short* __restrict__ A, const unsigned short* __restrict__ Bt,
    const float* __restrict__ ssp, const float* __restrict__ cb,
    float* __restrict__ out)
{
  __shared__ short8 Asm[2][GRAN];
  __shared__ short8 Bsm[2][GRAN];
  __shared__ float bias_sm[BN];

  const int tid = threadIdx.x;
  const int bid = blockIdx.x;
  const int tn = bid % (OUT_D / BN);
  const int tm = bid / (OUT_D / BN);
  const int m0 = tm * BM, n0 = tn * BN;
  const int lane = tid & 63, wid = tid >> 6;
  const int wm = wid >> 1, wn = wid & 1;
  const int lrow = lane & 15, lkb = lane >> 4;

  if (tid < BN) {
    int o = n0 + tid;
    float s = 0.f;
    #pragma unroll
    for (int f = 0; f < NUM_F; ++f) s += cb[f * OUT_D + o];
    bias_sm[tid] = s * ssp[o];
  }

  // staging: granule g = wid*256 + c*64 + lane; kc = g>>7, row = g&127
  const unsigned short* gA[4];
  const unsigned short* gB[4];
  #pragma unroll
  for (int c = 0; c < 4; ++c) {
    int g = wid * 256 + c * 64 + lane;
    int kc = g >> 7, row = g & 127;
    gA[c] = A + (size_t)(m0 + row) * KTOT + kc * 8;
    gB[c] = Bt + (size_t)(n0 + row) * KTOT + kc * 8;
  }

  auto STAGE = [&](int buf, int t) {
    const int koff = t * BK;
    #pragma unroll
    for (int c = 0; c < 4; ++c) {
      __builtin_amdgcn_global_load_lds(
          (const __attribute__((address_space(1))) void*)(gA[c] + koff),
          (__attribute__((address_space(3))) void*)&Asm[buf][wid * 256 + c * 64],
          16, 0, 0);
      __builtin_amdgcn_global_load_lds(
          (const __attribute__((address_space(1))) void*)(gB[c] + koff),
          (__attribute__((address_space(3))) void*)&Bsm[buf][wid * 256 + c * 64],
          16, 0, 0);
    }
  };

  f32x4 acc[4][4];
  #pragma unroll
  for (int i = 0; i < 4; ++i)
    #pragma unroll
    for (int j = 0; j < 4; ++j)
      acc[i][j] = (f32x4){0.f, 0.f, 0.f, 0.f};

  STAGE(0, 0);
  for (int t = 0; t < NT; ++t) {
    const int cur = t & 1;
    __syncthreads();                 // tile t staged; buf cur^1 free
    if (t + 1 < NT) STAGE(cur ^ 1, t + 1);   // overlap next-tile loads with MFMA
    #pragma unroll
    for (int kk = 0; kk < 2; ++kk) {
      short8 af[4], bfr[4];
      #pragma unroll
      for (int q = 0; q < 4; ++q) {
        int base = (kk * 4 + lkb) * 128 + q * 16 + lrow;
        af[q]  = Asm[cur][base + wm * 64];
        bfr[q] = Bsm[cur][base + wn * 64];
      }
      #pragma unroll
      for (int i = 0; i < 4; ++i)
        #pragma unroll
        for (int j = 0; j < 4; ++j)
          acc[i][j] = __builtin_amdgcn_mfma_f32_16x16x32_bf16(af[i], bfr[j], acc[i][j], 0, 0, 0);
    }
  }

  // epilogue: C/D layout col=lane&15, row=(lane>>4)*4+reg  (verified round 1)
  #pragma unroll
  for (int i = 0; i < 4; ++i) {
    int row = m0 + wm * 64 + i * 16 + lkb * 4;
    #pragma unroll
    for (int j = 0; j < 4; ++j) {
      int col = n0 + wn * 64 + j * 16 + lrow;
      float bia = bias_sm[wn * 64 + j * 16 + lrow];
      float* op = out + (size_t)row * OUT_D + col;
      op[0 * OUT_D] = acc[i][j][0] + bia;
      op[1 * OUT_D] = acc[i][j][1] + bia;
      op[2 * OUT_D] = acc[i][j][2] + bia;
      op[3 * OUT_D] = acc[i][j][3] + bia;
    }
  }
}

// ---------------------------------------------------------------------------
// Fallback: round-1 fused kernel (used only if ws too small). Verified correct.
// ---------------------------------------------------------------------------
#define FBK 32
#define FNT (KTOT / FBK)

__global__ __launch_bounds__(256, 2) void skan_fused(
    const float* __restrict__ x, const float* __restrict__ bw,
    const float* __restrict__ grid, const float* __restrict__ ssp,
    const float* __restrict__ coef, const float* __restrict__ cw,
    const float* __restrict__ cb, float* __restrict__ out)
{
  __shared__ short8 Asm[2][512];
  __shared__ short8 Bsm[2][512];
  __shared__ float bias_sm[BN];

  const int tid = threadIdx.x;
  const int bid = blockIdx.x;
  const int tn = bid % (OUT_D / BN);
  const int tm = bid / (OUT_D / BN);
  const int m0 = tm * BM, n0 = tn * BN;
  const int lane = tid & 63, wid = tid >> 6;
  const int wm = wid >> 1, wn = wid & 1;
  const int lrow = lane & 15, lkb = lane >> 4;

  if (tid < BN) {
    int o = n0 + tid;
    float s = 0.f;
    #pragma unroll
    for (int f = 0; f < NUM_F; ++f) s += cb[f * OUT_D + o];
    bias_sm[tid] = s * ssp[o];
  }

  const int rA = tid >> 1;
  const int hA = tid & 1;
  const float* xrow = x + (size_t)(m0 + rA) * IN_D + hA * 16;
  const int oB = n0 + rA;
  const float sspB = ssp[oB];
  const int g0 = hA * 2 * 128 + rA;
  const int g1 = g0 + 128;

  f32x4 xa[4], wb[4];

  auto LD = [&](int p_, int i0_) {
    const f32x4* xp = (const f32x4*)(xrow + i0_);
    xa[0] = xp[0]; xa[1] = xp[1]; xa[2] = xp[2]; xa[3] = xp[3];
    const float* wbase = (p_ == 0)
        ? (bw + (size_t)oB * IN_D)
        : (cw + ((size_t)(p_ - 1) * OUT_D + oB) * IN_D);
    const f32x4* wp = (const f32x4*)(wbase + hA * 16 + i0_);
    wb[0] = wp[0]; wb[1] = wp[1]; wb[2] = wp[2]; wb[3] = wp[3];
  };

  auto STG = [&](int buf, int p_, int i0_) {
    float v[16];
    #pragma unroll
    for (int q = 0; q < 4; ++q)
      #pragma unroll
      for (int e = 0; e < 4; ++e) v[q * 4 + e] = xa[q][e];

    unsigned short abf[16];
    if (p_ == 0) {
      #pragma unroll
      for (int j = 0; j < 16; ++j) {
        float t = v[j];
        float den = 1.f + __expf(-t);
        abf[j] = f2bf(t * __builtin_amdgcn_rcpf(den));
      }
    } else {
      float g = grid[p_ - 1];
      const float* cp = coef + (size_t)(i0_ + hA * 16) * NUM_F + (p_ - 1);
      #pragma unroll
      for (int j = 0; j < 16; ++j)
        abf[j] = f2bf(__sinf(v[j] * g) * cp[j * NUM_F]);
    }
    short8 s0, s1;
    #pragma unroll
    for (int e = 0; e < 8; ++e) { s0[e] = (short)abf[e]; s1[e] = (short)abf[8 + e]; }
    Asm[buf][g0] = s0;
    Asm[buf][g1] = s1;

    const float fac = (p_ == 0) ? 1.f : sspB;
    unsigned short bbf[16];
    #pragma unroll
    for (int q = 0; q < 4; ++q)
      #pragma unroll
      for (int e = 0; e < 4; ++e) bbf[q * 4 + e] = f2bf(wb[q][e] * fac);
    short8 t0, t1;
    #pragma unroll
    for (int e = 0; e < 8; ++e) { t0[e] = (short)bbf[e]; t1[e] = (short)bbf[8 + e]; }
    Bsm[buf][g0] = t0;
    Bsm[buf][g1] = t1;
  };

  f32x4 acc[4][4];
  #pragma unroll
  for (int i = 0; i < 4; ++i)
    #pragma unroll
    for (int j = 0; j < 4; ++j)
      acc[i][j] = (f32x4){0.f, 0.f, 0.f, 0.f};

  int p = 0, i0 = 0;
  LD(0, 0);
  STG(0, 0, 0);
  __syncthreads();

  for (int t = 0; t < FNT; ++t) {
    const int cur = t & 1;
    int p1 = p, i1 = i0 + FBK;
    if (i1 == IN_D) { i1 = 0; p1 = p + 1; }
    if (t + 1 < FNT) LD(p1, i1);

    short8 af[4], bfr[4];
    #pragma unroll
    for (int q = 0; q < 4; ++q) {
      af[q]  = Asm[cur][lkb * 128 + wm * 64 + q * 16 + lrow];
      bfr[q] = Bsm[cur][lkb * 128 + wn * 64 + q * 16 + lrow];
    }
    #pragma unroll
    for (int i = 0; i < 4; ++i)
      #pragma unroll
      for (int j = 0; j < 4; ++j)
        acc[i][j] = __builtin_amdgcn_mfma_f32_16x16x32_bf16(af[i], bfr[j], acc[i][j], 0, 0, 0);

    if (t + 1 < FNT) STG(cur ^ 1, p1, i1);
    p = p1; i0 = i1;
    __syncthreads();
  }

  #pragma unroll
  for (int i = 0; i < 4; ++i) {
    int row = m0 + wm * 64 + i * 16 + lkb * 4;
    #pragma unroll
    for (int j = 0; j < 4; ++j) {
      int col = n0 + wn * 64 + j * 16 + lrow;
      float bia = bias_sm[wn * 64 + j * 16 + lrow];
      float* op = out + (size_t)row * OUT_D + col;
      op[0 * OUT_D] = acc[i][j][0] + bia;
      op[1 * OUT_D] = acc[i][j][1] + bia;
      op[2 * OUT_D] = acc[i][j][2] + bia;
      op[3 * OUT_D] = acc[i][j][3] + bia;
    }
  }
}

extern "C" void kernel_launch(void* const* d_in, const int* in_sizes, int n_in,
                              void* d_out, int out_size, void* d_ws, size_t ws_size,
                              hipStream_t stream) {
  (void)in_sizes; (void)n_in; (void)out_size;
  const float* x    = (const float*)d_in[0];
  const float* bw   = (const float*)d_in[1];
  const float* grid = (const float*)d_in[2];
  const float* ssp  = (const float*)d_in[3];
  const float* coef = (const float*)d_in[4];
  const float* cw   = (const float*)d_in[5];
  const float* cb   = (const float*)d_in[6];
  float* out = (float*)d_out;

  const size_t A_bytes = (size_t)M_TOTAL * KTOT * 2;   // 173,408,256
  const size_t B_bytes = (size_t)OUT_D * KTOT * 2;     //  10,616,832

  if (ws_size >= A_bytes + B_bytes) {
    unsigned short* Aw = (unsigned short*)d_ws;
    unsigned short* Bw = (unsigned short*)((char*)d_ws + A_bytes);
    pack_a<<<(M_TOTAL * 96) / 256, 256, 0, stream>>>(x, grid, coef, Aw);
    pack_b<<<(OUT_D * NP * 96) / 256, 256, 0, stream>>>(bw, ssp, cw, Bw);
    skan_gemm<<<(M_TOTAL / BM) * (OUT_D / BN), 256, 0, stream>>>(Aw, Bw, ssp, cb, out);
  } else {
    skan_fused<<<(M_TOTAL / BM) * (OUT_D / BN), 256, 0, stream>>>(
        x, bw, grid, ssp, coef, cw, cb, out);
  }
}

// Round 5
// 436.336 us; speedup vs baseline: 1.6333x; 1.4962x over previous
//
#include <hip/hip_runtime.h>

#define M_TOTAL 12544
#define IN_D 768
#define OUT_D 768
#define NUM_F 8
#define NP 9
#define KTOT (IN_D * NP)            // 6912

#define BM 128
#define BN 128
#define BK 64
#define MT_TILES (M_TOTAL / BM)     // 98
#define NT_TILES (OUT_D / BN)       // 6
#define KT_TILES (KTOT / BK)        // 108
#define GRAN 1024                   // granules (16B) per 128x64 bf16 tile

typedef __attribute__((ext_vector_type(8))) short short8;
typedef __attribute__((ext_vector_type(4))) float f32x4;

__device__ __forceinline__ unsigned short f2bf(float f) {
  unsigned u = __float_as_uint(f);
  u += 0x7fff + ((u >> 16) & 1);   // RNE
  return (unsigned short)(u >> 16);
}

// ---------------------------------------------------------------------------
// pack_a_t: A in tile-major granule order.
// At[(mt*108 + kt)*1024 + g], g = kc*128 + row (kc = k8-chunk 0..7, row 0..127)
// value = p==0 ? silu(x[m,i]) : sin(grid[p-1]*x[m,i])*coef[i,p-1]
// where kt = p*12 + j, i = j*64 + kc*8 + e. One block per (mt, kt).
// ---------------------------------------------------------------------------
__global__ __launch_bounds__(256) void pack_a_t(
    const float* __restrict__ x, const float* __restrict__ grid,
    const float* __restrict__ coef, short8* __restrict__ At)
{
  __shared__ float xs[128][68];   // +4 pad: 4-way max on strided reads
  __shared__ float cs[64];
  __shared__ float gsh;

  const int bid = blockIdx.x;
  const int mt = bid / KT_TILES;
  const int kt = bid % KT_TILES;
  const int p = kt / 12, j = kt % 12;
  const int tid = threadIdx.x;

  // stage x slice: rows mt*128..+127, cols j*64..+63 (coalesced 128B/thread)
  {
    int row = tid >> 1, half = tid & 1;
    const f32x4* sp = (const f32x4*)(x + (size_t)(mt * 128 + row) * IN_D + j * 64 + half * 32);
    #pragma unroll
    for (int e = 0; e < 8; ++e)
      *(f32x4*)&xs[row][half * 32 + e * 4] = sp[e];
  }
  if (p > 0) {
    if (tid < 64) cs[tid] = coef[(size_t)(j * 64 + tid) * NUM_F + (p - 1)];
    if (tid == 0) gsh = grid[p - 1];
  }
  __syncthreads();

  short8* dst = At + ((size_t)mt * KT_TILES + kt) * GRAN;
  if (p == 0) {
    #pragma unroll
    for (int c = 0; c < 4; ++c) {
      int g = c * 256 + tid, row = g & 127, kc = g >> 7;
      short8 s;
      #pragma unroll
      for (int e = 0; e < 8; ++e) {
        float t = xs[row][kc * 8 + e];
        s[e] = (short)f2bf(t / (1.f + __expf(-t)));
      }
      dst[g] = s;   // consecutive lanes -> consecutive 16B: coalesced
    }
  } else {
    float gf = gsh;
    #pragma unroll
    for (int c = 0; c < 4; ++c) {
      int g = c * 256 + tid, row = g & 127, kc = g >> 7;
      short8 s;
      #pragma unroll
      for (int e = 0; e < 8; ++e)
        s[e] = (short)f2bf(__sinf(xs[row][kc * 8 + e] * gf) * cs[kc * 8 + e]);
      dst[g] = s;
    }
  }
}

// ---------------------------------------------------------------------------
// pack_b_t: Bt[(nt*108 + kt)*1024 + g] = (p==0 ? bw[o][i] : cw[p-1][o][i]*ssp[o])
// o = nt*128 + row, i = j*64 + kc*8. One thread per granule.
// ---------------------------------------------------------------------------
__global__ __launch_bounds__(256) void pack_b_t(
    const float* __restrict__ bw, const float* __restrict__ ssp,
    const float* __restrict__ cw, short8* __restrict__ Bt)
{
  int gg = blockIdx.x * 256 + threadIdx.x;   // [0, 6*108*1024)
  int nt = gg / (KT_TILES * GRAN);
  int rem = gg % (KT_TILES * GRAN);
  int kt = rem >> 10;
  int g = rem & 1023;
  int row = g & 127, kc = g >> 7;
  int o = nt * 128 + row;
  int p = kt / 12, j = kt % 12;
  int i0 = j * 64 + kc * 8;
  const float* src = (p == 0) ? bw + (size_t)o * IN_D + i0
                              : cw + ((size_t)(p - 1) * OUT_D + o) * IN_D + i0;
  float fac = (p == 0) ? 1.f : ssp[o];
  f32x4 v0 = ((const f32x4*)src)[0], v1 = ((const f32x4*)src)[1];
  short8 s;
  #pragma unroll
  for (int e = 0; e < 4; ++e) {
    s[e]     = (short)f2bf(v0[e] * fac);
    s[e + 4] = (short)f2bf(v1[e] * fac);
  }
  Bt[gg] = s;
}

// ---------------------------------------------------------------------------
// skan_gemm: pure bf16 GEMM on tile-major inputs. 128x128, BK=64, 4 waves,
// dbuf LDS, global_load_lds width-16 on fully-sequential addresses.
// ---------------------------------------------------------------------------
__global__ __launch_bounds__(256, 2) void skan_gemm(
    const short8* __restrict__ At, const short8* __restrict__ Bt,
    const float* __restrict__ ssp, const float* __restrict__ cb,
    float* __restrict__ out)
{
  __shared__ short8 Asm[2][GRAN];
  __shared__ short8 Bsm[2][GRAN];
  __shared__ float bias_sm[BN];

  // bijective XCD swizzle (nwg=588 = 8*73+4): all 6 n-blocks of an m-tile
  // land on one XCD -> A-panel shared in that XCD's L2.
  const int bid0 = blockIdx.x;
  const int xcd = bid0 & 7;
  const int idx = bid0 >> 3;
  const int wgid = (xcd < 4 ? xcd * 74 : 4 * 74 + (xcd - 4) * 73) + idx;
  const int tm = wgid / NT_TILES, tn = wgid % NT_TILES;
  const int m0 = tm * BM, n0 = tn * BN;

  const int tid = threadIdx.x;
  const int lane = tid & 63, wid = tid >> 6;
  const int wm = wid >> 1, wn = wid & 1;
  const int lrow = lane & 15, lkb = lane >> 4;

  if (tid < BN) {
    int o = n0 + tid;
    float s = 0.f;
    #pragma unroll
    for (int f = 0; f < NUM_F; ++f) s += cb[f * OUT_D + o];
    bias_sm[tid] = s * ssp[o];
  }

  const short8* Abase = At + (size_t)tm * KT_TILES * GRAN;
  const short8* Bbase = Bt + (size_t)tn * KT_TILES * GRAN;

  auto STAGE = [&](int buf, int t) {
    const short8* as = Abase + (size_t)t * GRAN;
    const short8* bs = Bbase + (size_t)t * GRAN;
    #pragma unroll
    for (int c = 0; c < 4; ++c) {
      __builtin_amdgcn_global_load_lds(
          (const __attribute__((address_space(1))) void*)(as + c * 256 + tid),
          (__attribute__((address_space(3))) void*)&Asm[buf][c * 256 + tid],
          16, 0, 0);
      __builtin_amdgcn_global_load_lds(
          (const __attribute__((address_space(1))) void*)(bs + c * 256 + tid),
          (__attribute__((address_space(3))) void*)&Bsm[buf][c * 256 + tid],
          16, 0, 0);
    }
  };

  f32x4 acc[4][4];
  #pragma unroll
  for (int i = 0; i < 4; ++i)
    #pragma unroll
    for (int j = 0; j < 4; ++j)
      acc[i][j] = (f32x4){0.f, 0.f, 0.f, 0.f};

  STAGE(0, 0);
  for (int t = 0; t < KT_TILES; ++t) {
    const int cur = t & 1;
    __syncthreads();                          // tile t landed; buf cur^1 free
    if (t + 1 < KT_TILES) STAGE(cur ^ 1, t + 1);
    #pragma unroll
    for (int kk = 0; kk < 2; ++kk) {
      short8 af[4], bfr[4];
      #pragma unroll
      for (int q = 0; q < 4; ++q) {
        int base = (kk * 4 + lkb) * 128 + q * 16 + lrow;
        af[q]  = Asm[cur][base + wm * 64];
        bfr[q] = Bsm[cur][base + wn * 64];
      }
      #pragma unroll
      for (int i = 0; i < 4; ++i)
        #pragma unroll
        for (int j = 0; j < 4; ++j)
          acc[i][j] = __builtin_amdgcn_mfma_f32_16x16x32_bf16(af[i], bfr[j], acc[i][j], 0, 0, 0);
    }
  }

  // epilogue: C/D layout col=lane&15, row=(lane>>4)*4+reg  (verified round 1)
  #pragma unroll
  for (int i = 0; i < 4; ++i) {
    int row = m0 + wm * 64 + i * 16 + lkb * 4;
    #pragma unroll
    for (int j = 0; j < 4; ++j) {
      int col = n0 + wn * 64 + j * 16 + lrow;
      float bia = bias_sm[wn * 64 + j * 16 + lrow];
      float* op = out + (size_t)row * OUT_D + col;
      op[0 * OUT_D] = acc[i][j][0] + bia;
      op[1 * OUT_D] = acc[i][j][1] + bia;
      op[2 * OUT_D] = acc[i][j][2] + bia;
      op[3 * OUT_D] = acc[i][j][3] + bia;
    }
  }
}

extern "C" void kernel_launch(void* const* d_in, const int* in_sizes, int n_in,
                              void* d_out, int out_size, void* d_ws, size_t ws_size,
                              hipStream_t stream) {
  (void)in_sizes; (void)n_in; (void)out_size; (void)ws_size;
  const float* x    = (const float*)d_in[0];
  const float* bw   = (const float*)d_in[1];
  const float* grid = (const float*)d_in[2];
  const float* ssp  = (const float*)d_in[3];
  const float* coef = (const float*)d_in[4];
  const float* cw   = (const float*)d_in[5];
  const float* cb   = (const float*)d_in[6];
  float* out = (float*)d_out;

  const size_t A_bytes = (size_t)MT_TILES * KT_TILES * GRAN * 16;  // 173,408,256
  short8* Aw = (short8*)d_ws;
  short8* Bw = (short8*)((char*)d_ws + A_bytes);

  pack_a_t<<<MT_TILES * KT_TILES, 256, 0, stream>>>(x, grid, coef, Aw);
  pack_b_t<<<(NT_TILES * KT_TILES * GRAN) / 256, 256, 0, stream>>>(bw, ssp, cw, Bw);
  skan_gemm<<<MT_TILES * NT_TILES, 256, 0, stream>>>(Aw, Bw, ssp, cb, out);
}

// Round 7
// 296.980 us; speedup vs baseline: 2.3997x; 1.4692x over previous
//
#include <hip/hip_runtime.h>

#define M_TOTAL 12544
#define IN_D 768
#define OUT_D 768
#define NUM_F 8
#define NP 9
#define KTOT (IN_D * NP)            // 6912

#define BM 128
#define BN 128
#define BK 32
#define MT_TILES (M_TOTAL / BM)     // 98
#define NT_TILES (OUT_D / BN)       // 6
#define PJ (IN_D / BK)              // 24 k-chunks per plane
#define KT_TILES (KTOT / BK)        // 216
#define GRANA 512                   // 16B granules per 128x32 bf16 tile

typedef __attribute__((ext_vector_type(8))) short short8;
typedef __attribute__((ext_vector_type(4))) float f32x4;

__device__ __forceinline__ unsigned short f2bf(float f) {
  unsigned u = __float_as_uint(f);
  u += 0x7fff + ((u >> 16) & 1);   // RNE
  return (unsigned short)(u >> 16);
}

// ---------------------------------------------------------------------------
// pack_a_t: one block per (mt, jj) = (m-tile, 32-col slice). Computes all 9
// planes from one x staging: x read from HBM exactly once (38.5 MB total).
// Output granule order matches GEMM: At[(mt*216 + p*24 + jj)*512 + kc*128+row],
// granule = bf16 A[row][jj*32 + kc*8 .. +7].
// LDS transposed (xs[col][row]) with 129-row pitch: staging writes and granule
// reads are both bank-conflict-free.
// ---------------------------------------------------------------------------
__global__ __launch_bounds__(256) void pack_a_t(
    const float* __restrict__ x, const float* __restrict__ grid,
    const float* __restrict__ coef, short8* __restrict__ At)
{
  __shared__ float xs[32][129];
  __shared__ float cs[32][8];

  const int bid = blockIdx.x;
  const int mt = bid / PJ, jj = bid % PJ;
  const int tid = threadIdx.x;

  // stage x rows 0..127, cols jj*32..+31. 8 lanes cover one row's 128B:
  // fully coalesced; LDS write banks = (4c+e+r)%32 -> <=2-way (free).
  {
    const int c = tid & 7;          // 4-col chunk
    const int r0 = tid >> 3;        // row within 32-row group
    #pragma unroll
    for (int q = 0; q < 4; ++q) {
      int r = q * 32 + r0;
      f32x4 v = *(const f32x4*)(x + (size_t)(mt * 128 + r) * IN_D + jj * 32 + c * 4);
      #pragma unroll
      for (int e = 0; e < 4; ++e) xs[c * 4 + e][r] = v[e];
    }
  }
  // stage coef slice [32 cols][8 freqs] (coalesced: consecutive tid -> addr)
  cs[tid >> 3][tid & 7] = coef[(size_t)(jj * 32 + (tid >> 3)) * NUM_F + (tid & 7)];
  __syncthreads();

  for (int p = 0; p < NP; ++p) {
    short8* dst = At + ((size_t)mt * KT_TILES + p * PJ + jj) * GRANA;
    float gf = (p > 0) ? grid[p - 1] : 0.f;
    #pragma unroll
    for (int c2 = 0; c2 < 2; ++c2) {
      int g = c2 * 256 + tid;
      int row = g & 127, kc = g >> 7;
      short8 s;
      if (p == 0) {
        #pragma unroll
        for (int e = 0; e < 8; ++e) {
          float t = xs[kc * 8 + e][row];
          s[e] = (short)f2bf(t / (1.f + __expf(-t)));
        }
      } else {
        #pragma unroll
        for (int e = 0; e < 8; ++e) {
          float t = xs[kc * 8 + e][row];
          s[e] = (short)f2bf(__sinf(t * gf) * cs[kc * 8 + e][p - 1]);
        }
      }
      dst[g] = s;   // consecutive lanes -> consecutive 16B: coalesced
    }
  }
}

// ---------------------------------------------------------------------------
// pack_b_t: Bt[(nt*216 + kt)*512 + g] = (p==0 ? bw[o][i] : cw[p-1][o][i]*ssp[o])
// o = nt*128 + row, i = jj*32 + kc*8, kt = p*24 + jj. One thread per granule.
// ---------------------------------------------------------------------------
__global__ __launch_bounds__(256) void pack_b_t(
    const float* __restrict__ bw, const float* __restrict__ ssp,
    const float* __restrict__ cw, short8* __restrict__ Bt)
{
  int gg = blockIdx.x * 256 + threadIdx.x;   // [0, 6*216*512)
  int nt = gg / (KT_TILES * GRANA);
  int rem = gg % (KT_TILES * GRANA);
  int kt = rem >> 9;
  int g = rem & 511;
  int row = g & 127, kc = g >> 7;
  int o = nt * 128 + row;
  int p = kt / PJ, jj = kt % PJ;
  int i0 = jj * 32 + kc * 8;
  const float* src = (p == 0) ? bw + (size_t)o * IN_D + i0
                              : cw + ((size_t)(p - 1) * OUT_D + o) * IN_D + i0;
  float fac = (p == 0) ? 1.f : ssp[o];
  f32x4 v0 = ((const f32x4*)src)[0], v1 = ((const f32x4*)src)[1];
  short8 s;
  #pragma unroll
  for (int e = 0; e < 4; ++e) {
    s[e]     = (short)f2bf(v0[e] * fac);
    s[e + 4] = (short)f2bf(v1[e] * fac);
  }
  Bt[gg] = s;
}

// ---------------------------------------------------------------------------
// skan_gemm: bf16 GEMM on tile-major inputs. 128x128 tile, BK=32, 4 waves,
// dbuf LDS (33 KB -> 4 blocks/CU resident, 16 waves/CU: cross-block overlap
// hides the per-k-step staging drain), global_load_lds width-16 sequential.
// ---------------------------------------------------------------------------
__global__ __launch_bounds__(256, 4) void skan_gemm(
    const short8* __restrict__ At, const short8* __restrict__ Bt,
    const float* __restrict__ ssp, const float* __restrict__ cb,
    float* __restrict__ out)
{
  __shared__ short8 Asm[2][GRANA];
  __shared__ short8 Bsm[2][GRANA];
  __shared__ float bias_sm[BN];

  // bijective XCD swizzle (nwg=588 = 8*73+4): all 6 n-blocks of an m-tile
  // land on one XCD -> A-panel shared in that XCD's L2.
  const int bid0 = blockIdx.x;
  const int xcd = bid0 & 7;
  const int idx = bid0 >> 3;
  const int wgid = (xcd < 4 ? xcd * 74 : 4 * 74 + (xcd - 4) * 73) + idx;
  const int tm = wgid / NT_TILES, tn = wgid % NT_TILES;
  const int m0 = tm * BM, n0 = tn * BN;

  const int tid = threadIdx.x;
  const int lane = tid & 63, wid = tid >> 6;
  const int wm = wid >> 1, wn = wid & 1;
  const int lrow = lane & 15, lkb = lane >> 4;

  if (tid < BN) {
    int o = n0 + tid;
    float s = 0.f;
    #pragma unroll
    for (int f = 0; f < NUM_F; ++f) s += cb[f * OUT_D + o];
    bias_sm[tid] = s * ssp[o];
  }

  const short8* Abase = At + (size_t)tm * KT_TILES * GRANA;
  const short8* Bbase = Bt + (size_t)tn * KT_TILES * GRANA;

  auto STAGE = [&](int buf, int t) {
    const short8* as = Abase + (size_t)t * GRANA;
    const short8* bs = Bbase + (size_t)t * GRANA;
    #pragma unroll
    for (int c = 0; c < 2; ++c) {
      __builtin_amdgcn_global_load_lds(
          (const __attribute__((address_space(1))) void*)(as + c * 256 + tid),
          (__attribute__((address_space(3))) void*)&Asm[buf][c * 256 + tid],
          16, 0, 0);
      __builtin_amdgcn_global_load_lds(
          (const __attribute__((address_space(1))) void*)(bs + c * 256 + tid),
          (__attribute__((address_space(3))) void*)&Bsm[buf][c * 256 + tid],
          16, 0, 0);
    }
  };

  f32x4 acc[4][4];
  #pragma unroll
  for (int i = 0; i < 4; ++i)
    #pragma unroll
    for (int j = 0; j < 4; ++j)
      acc[i][j] = (f32x4){0.f, 0.f, 0.f, 0.f};

  STAGE(0, 0);
  for (int t = 0; t < KT_TILES; ++t) {
    const int cur = t & 1;
    __syncthreads();                          // tile t landed; buf cur^1 free
    if (t + 1 < KT_TILES) STAGE(cur ^ 1, t + 1);
    short8 af[4], bfr[4];
    #pragma unroll
    for (int q = 0; q < 4; ++q) {
      int base = lkb * 128 + q * 16 + lrow;   // granule = kc*128 + row, kc=lkb
      af[q]  = Asm[cur][base + wm * 64];
      bfr[q] = Bsm[cur][base + wn * 64];
    }
    #pragma unroll
    for (int i = 0; i < 4; ++i)
      #pragma unroll
      for (int j = 0; j < 4; ++j)
        acc[i][j] = __builtin_amdgcn_mfma_f32_16x16x32_bf16(af[i], bfr[j], acc[i][j], 0, 0, 0);
  }

  // epilogue: C/D layout col=lane&15, row=(lane>>4)*4+reg  (verified round 1)
  #pragma unroll
  for (int i = 0; i < 4; ++i) {
    int row = m0 + wm * 64 + i * 16 + lkb * 4;
    #pragma unroll
    for (int j = 0; j < 4; ++j) {
      int col = n0 + wn * 64 + j * 16 + lrow;
      float bia = bias_sm[wn * 64 + j * 16 + lrow];
      float* op = out + (size_t)row * OUT_D + col;
      op[0 * OUT_D] = acc[i][j][0] + bia;
      op[1 * OUT_D] = acc[i][j][1] + bia;
      op[2 * OUT_D] = acc[i][j][2] + bia;
      op[3 * OUT_D] = acc[i][j][3] + bia;
    }
  }
}

extern "C" void kernel_launch(void* const* d_in, const int* in_sizes, int n_in,
                              void* d_out, int out_size, void* d_ws, size_t ws_size,
                              hipStream_t stream) {
  (void)in_sizes; (void)n_in; (void)out_size; (void)ws_size;
  const float* x    = (const float*)d_in[0];
  const float* bw   = (const float*)d_in[1];
  const float* grid = (const float*)d_in[2];
  const float* ssp  = (const float*)d_in[3];
  const float* coef = (const float*)d_in[4];
  const float* cw   = (const float*)d_in[5];
  const float* cb   = (const float*)d_in[6];
  float* out = (float*)d_out;

  const size_t A_bytes = (size_t)MT_TILES * KT_TILES * GRANA * 16;  // 173,408,256
  short8* Aw = (short8*)d_ws;
  short8* Bw = (short8*)((char*)d_ws + A_bytes);

  pack_a_t<<<MT_TILES * PJ, 256, 0, stream>>>(x, grid, coef, Aw);
  pack_b_t<<<(NT_TILES * KT_TILES * GRANA) / 256, 256, 0, stream>>>(bw, ssp, cw, Bw);
  skan_gemm<<<MT_TILES * NT_TILES, 256, 0, stream>>>(Aw, Bw, ssp, cb, out);
}